// Round 2
// baseline (17.562 us; speedup 1.0000x reference)
//
#include <hip/hip_runtime.h>
#include <float.h>

// SpanMaxPooler: out[b, i*H + h] = valid(b,i) ? max_{s in [start,end)} hidden[b,s,h]
//                                            : missing[i,h]
// B=64, S=512, H=1024, I=2. Spans are 1..32 rows. Latency-bound tiny kernel.
//
// Strategy: parallelize the span (row) dimension across 4 wave-uniform
// row-groups so the dependent-load chain is ONE load latency, not eight.
// Loads are clamped (s = min(.., n-1)) instead of predicated: max is
// idempotent, so redundant re-reads of the last row are harmless and the
// 8 loads per thread issue unconditionally back-to-back.

#define FMAX4(a, v)            \
    a.x = fmaxf(a.x, (v).x);   \
    a.y = fmaxf(a.y, (v).y);   \
    a.z = fmaxf(a.z, (v).z);   \
    a.w = fmaxf(a.w, (v).w);

template <int S, int H, int I, int SPLIT, int RG>
__global__ __launch_bounds__((H / SPLIT / 4) * RG) void span_max_kernel(
    const float* __restrict__ hidden,   // [B,S,H]
    const int*   __restrict__ start,    // [B,I]
    const int*   __restrict__ end,      // [B,I]
    const float* __restrict__ missing,  // [I,H]
    float*       __restrict__ out)      // [B,I*H]
{
    constexpr int COLS    = H / SPLIT / 4;  // float4 column slots per block (128)
    constexpr int MAXROWS = 32;             // span length guaranteed <= 32
    constexpr int PER     = MAXROWS / RG;   // loads per thread (8)

    __shared__ float4 partials[RG - 1][COLS];

    const int blk  = blockIdx.x;
    const int part = blk % SPLIT;
    const int span = blk / SPLIT;           // b*I + i
    const int b    = span / I;
    const int i    = span % I;

    const int col = threadIdx.x % COLS;     // contiguous within wave -> coalesced
    const int rg  = threadIdx.x / COLS;     // wave-uniform row group (COLS=128 = 2 waves)
    const int h0  = part * (H / SPLIT) + col * 4;

    const int s0 = start[span];             // scalar loads (block-uniform)
    const int s1 = end[span];

    if (s0 < 0 || s1 < 0) {                 // block-uniform branch
        if (rg == 0) {
            float4 v = *reinterpret_cast<const float4*>(&missing[(size_t)i * H + h0]);
            *reinterpret_cast<float4*>(&out[(size_t)span * H + h0]) = v;
        }
        return;
    }

    const int n = s1 - s0;                  // 1..32
    const float* base = hidden + (size_t)b * S * H + (size_t)s0 * H + h0;

    // 8 independent clamped loads, all in flight before any use.
    float4 v[PER];
    #pragma unroll
    for (int k = 0; k < PER; ++k) {
        const int s = min(rg + k * RG, n - 1);
        v[k] = *reinterpret_cast<const float4*>(base + (size_t)s * H);
    }

    float4 acc = v[0];
    #pragma unroll
    for (int k = 1; k < PER; ++k) { FMAX4(acc, v[k]); }

    // Cross-row-group reduction via LDS (3 partials + rg0's own).
    if (rg > 0) {
        partials[rg - 1][col] = acc;
    }
    __syncthreads();
    if (rg == 0) {
        #pragma unroll
        for (int r = 0; r < RG - 1; ++r) {
            FMAX4(acc, partials[r][col]);
        }
        *reinterpret_cast<float4*>(&out[(size_t)span * H + h0]) = acc;
    }
}

extern "C" void kernel_launch(void* const* d_in, const int* in_sizes, int n_in,
                              void* d_out, int out_size, void* d_ws, size_t ws_size,
                              hipStream_t stream) {
    constexpr int B = 64, S = 512, H = 1024, I = 2;
    constexpr int SPLIT = 2;   // 2 blocks per (b,i) -> 256 blocks (1/CU)
    constexpr int RG    = 4;   // row-groups per block

    const float* hidden  = (const float*)d_in[0];
    const int*   start   = (const int*)d_in[1];
    const int*   end     = (const int*)d_in[2];
    const float* missing = (const float*)d_in[3];
    float*       out     = (float*)d_out;

    const int grid  = B * I * SPLIT;          // 256
    const int block = (H / SPLIT / 4) * RG;   // 512 threads

    span_max_kernel<S, H, I, SPLIT, RG><<<grid, block, 0, stream>>>(
        hidden, start, end, missing, out);
}

// Round 3
// 9.411 us; speedup vs baseline: 1.8661x; 1.8661x over previous
//
#include <hip/hip_runtime.h>
#include <float.h>

// SpanMaxPooler: out[b, i*H + h] = valid(b,i) ? max_{s in [start,end)} hidden[b,s,h]
//                                            : missing[i,h]
// B=64, S=512, H=1024, I=2. Spans are 1..32 rows. Latency-bound tiny kernel.
//
// R3: identical structure to R1 (128-thread blocks, SPLIT=2, no LDS/barrier),
// but the span walk issues 8 independent CLAMPED loads per batch
// (min(s+k, n-1)) instead of 4 + predicated tail. Max is idempotent, so the
// clamp's duplicate reads of the last row are harmless L1 hits. This halves
// the dependent load-latency chain (avg ~4.2 -> ~2.1 serial groups).

#define FMAX4(a, v)            \
    a.x = fmaxf(a.x, (v).x);   \
    a.y = fmaxf(a.y, (v).y);   \
    a.z = fmaxf(a.z, (v).z);   \
    a.w = fmaxf(a.w, (v).w);

template <int S, int H, int I, int SPLIT>
__global__ __launch_bounds__(H / SPLIT / 4) void span_max_kernel(
    const float* __restrict__ hidden,   // [B,S,H]
    const int*   __restrict__ start,    // [B,I]
    const int*   __restrict__ end,      // [B,I]
    const float* __restrict__ missing,  // [I,H]
    float*       __restrict__ out)      // [B,I*H]
{
    constexpr int BATCH = 8;                 // independent loads in flight
    const int blk  = blockIdx.x;
    const int part = blk % SPLIT;
    const int span = blk / SPLIT;            // b*I + i
    const int b    = span / I;
    const int i    = span % I;
    const int h0   = part * (H / SPLIT) + threadIdx.x * 4;

    const int s0 = start[span];              // block-uniform
    const int s1 = end[span];

    float4 acc;
    if (s0 < 0 || s1 < 0) {                  // block-uniform branch
        acc = *reinterpret_cast<const float4*>(&missing[(size_t)i * H + h0]);
    } else {
        const int n = s1 - s0;               // 1..32
        const float* base = hidden + (size_t)b * S * H + (size_t)s0 * H + h0;

        // batch 0: rows 0..7 clamped to n-1 (dupes hit L1; max is idempotent)
        float4 v[BATCH];
        #pragma unroll
        for (int k = 0; k < BATCH; ++k) {
            v[k] = *reinterpret_cast<const float4*>(base + (size_t)min(k, n - 1) * H);
        }
        acc = v[0];
        #pragma unroll
        for (int k = 1; k < BATCH; ++k) { FMAX4(acc, v[k]); }

        // remaining batches (at most 3 iterations for n <= 32)
        for (int s = BATCH; s < n; s += BATCH) {
            #pragma unroll
            for (int k = 0; k < BATCH; ++k) {
                v[k] = *reinterpret_cast<const float4*>(base + (size_t)min(s + k, n - 1) * H);
            }
            #pragma unroll
            for (int k = 0; k < BATCH; ++k) { FMAX4(acc, v[k]); }
        }
    }

    *reinterpret_cast<float4*>(&out[(size_t)span * H + h0]) = acc;
}

extern "C" void kernel_launch(void* const* d_in, const int* in_sizes, int n_in,
                              void* d_out, int out_size, void* d_ws, size_t ws_size,
                              hipStream_t stream) {
    constexpr int B = 64, S = 512, H = 1024, I = 2;
    constexpr int SPLIT = 2;   // 2 blocks per (b,i) -> 256 blocks (1/CU)

    const float* hidden  = (const float*)d_in[0];
    const int*   start   = (const int*)d_in[1];
    const int*   end     = (const int*)d_in[2];
    const float* missing = (const float*)d_in[3];
    float*       out     = (float*)d_out;

    const int grid  = B * I * SPLIT;       // 256
    const int block = H / SPLIT / 4;       // 128 threads, float4 each

    span_max_kernel<S, H, I, SPLIT><<<grid, block, 0, stream>>>(
        hidden, start, end, missing, out);
}